// Round 1
// 1656.631 us; speedup vs baseline: 1.0418x; 1.0418x over previous
//
#include <hip/hip_runtime.h>
#include <math.h>

#define B_ 2
#define S_ 2048
#define D_ 1024
#define H_ 16
#define DEPTH_ 64
#define SCALE_ 0.125f   // 1/sqrt(64)

// ---------------------------------------------------------------------------
// 128x128 tile fp32 GEMM pieces. Block = 256 threads (16x16), 8x8 micro-tile
// split as 2x2 quadrants of 4x4 at +0/+64 so every LDS fragment read is a
// conflict-free ds_read_b128 (addresses 16B apart). As/Bs are [k][m]/[k][n]
// padded to 132 floats (rows stay 16B-aligned; staging writes <=2-way
// aliased, free on CDNA4). 64 FMA per 4 ds_read_b128 = 2 FLOP/LDS-byte, so
// the kernel is VALU-bound (157 TF roofline) instead of LDS-BW-bound.
// ---------------------------------------------------------------------------

// Fused Q/K/V projection: z selects (X, W, bias, dst). dst is head-split
// [B,H,S,64]. 768 blocks = 3 blocks/CU.
__global__ __launch_bounds__(256) void qkv_proj_kernel(
    const float* __restrict__ qx, const float* __restrict__ kx,
    const float* __restrict__ vx,
    const float* __restrict__ Wq, const float* __restrict__ bq,
    const float* __restrict__ Wk, const float* __restrict__ bk,
    const float* __restrict__ Wv, const float* __restrict__ bv,
    float* __restrict__ qh, float* __restrict__ kh, float* __restrict__ vh)
{
    const float* X; const float* W; const float* bias; float* out;
    if (blockIdx.z == 0)      { X = qx; W = Wq; bias = bq; out = qh; }
    else if (blockIdx.z == 1) { X = kx; W = Wk; bias = bk; out = kh; }
    else                      { X = vx; W = Wv; bias = bv; out = vh; }

    __shared__ float As[16][132];
    __shared__ float Bs[16][132];
    const int tid = threadIdx.x;
    const int tx = tid & 15, ty = tid >> 4;
    const int m0 = blockIdx.y * 128;
    const int n0 = blockIdx.x * 128;
    float acc[8][8] = {};

    for (int kk = 0; kk < D_; kk += 16) {
        int f = tid;
#pragma unroll
        for (int r = 0; r < 2; ++r, f += 256) {
            int m = f >> 2, k4 = (f & 3) << 2;
            float4 x = *(const float4*)&X[(size_t)(m0 + m) * D_ + kk + k4];
            As[k4 + 0][m] = x.x; As[k4 + 1][m] = x.y;
            As[k4 + 2][m] = x.z; As[k4 + 3][m] = x.w;
        }
        f = tid;
#pragma unroll
        for (int r = 0; r < 2; ++r, f += 256) {
            int k = f >> 5, n4 = (f & 31) << 2;
            *(float4*)&Bs[k][n4] = *(const float4*)&W[(size_t)(kk + k) * D_ + n0 + n4];
        }
        __syncthreads();
#pragma unroll
        for (int k = 0; k < 16; ++k) {
            float4 a0 = *(const float4*)&As[k][ty * 4];
            float4 a1 = *(const float4*)&As[k][64 + ty * 4];
            float4 b0 = *(const float4*)&Bs[k][tx * 4];
            float4 b1 = *(const float4*)&Bs[k][64 + tx * 4];
            float av[8]  = {a0.x, a0.y, a0.z, a0.w, a1.x, a1.y, a1.z, a1.w};
            float bv8[8] = {b0.x, b0.y, b0.z, b0.w, b1.x, b1.y, b1.z, b1.w};
#pragma unroll
            for (int i = 0; i < 8; ++i)
#pragma unroll
                for (int j = 0; j < 8; ++j) acc[i][j] += av[i] * bv8[j];
        }
        __syncthreads();
    }
    float4 bl = *(const float4*)&bias[n0 + tx * 4];
    float4 bh = *(const float4*)&bias[n0 + 64 + tx * 4];
#pragma unroll
    for (int ii = 0; ii < 8; ++ii) {
        int m = m0 + ((ii >> 2) << 6) + ty * 4 + (ii & 3);
        int b = m >> 11, s = m & 2047;
        int n = n0 + tx * 4;
        int h = n >> 6, d = n & 63;
        float4 lo = make_float4(acc[ii][0] + bl.x, acc[ii][1] + bl.y,
                                acc[ii][2] + bl.z, acc[ii][3] + bl.w);
        *(float4*)&out[((size_t)(b * H_ + h) * S_ + s) * DEPTH_ + d] = lo;
        n = n0 + 64 + tx * 4;
        h = n >> 6; d = n & 63;
        float4 hi = make_float4(acc[ii][4] + bh.x, acc[ii][5] + bh.y,
                                acc[ii][6] + bh.z, acc[ii][7] + bh.w);
        *(float4*)&out[((size_t)(b * H_ + h) * S_ + s) * DEPTH_ + d] = hi;
    }
}

// logits[z,i,j] = scale * dot(qh[z,i,:], kh[z,j,:]) - 1e9*mask[b,j]
__global__ __launch_bounds__(256) void logits_kernel(
    const float* __restrict__ qh, const float* __restrict__ kh,
    const float* __restrict__ mask, float* __restrict__ attn)
{
    const int z = blockIdx.z;            // b*H + h
    const int b = z >> 4;
    const float* A  = qh + (size_t)z * S_ * DEPTH_;
    const float* Bm = kh + (size_t)z * S_ * DEPTH_;
    __shared__ float As[16][132];
    __shared__ float Bs[16][132];
    const int tid = threadIdx.x;
    const int tx = tid & 15, ty = tid >> 4;
    const int m0 = blockIdx.y * 128;
    const int n0 = blockIdx.x * 128;
    float acc[8][8] = {};

    for (int kk = 0; kk < DEPTH_; kk += 16) {
        int f = tid;
#pragma unroll
        for (int r = 0; r < 2; ++r, f += 256) {
            int m = f >> 2, k4 = (f & 3) << 2;
            float4 x = *(const float4*)&A[(size_t)(m0 + m) * DEPTH_ + kk + k4];
            As[k4 + 0][m] = x.x; As[k4 + 1][m] = x.y;
            As[k4 + 2][m] = x.z; As[k4 + 3][m] = x.w;
            float4 y = *(const float4*)&Bm[(size_t)(n0 + m) * DEPTH_ + kk + k4];
            Bs[k4 + 0][m] = y.x; Bs[k4 + 1][m] = y.y;
            Bs[k4 + 2][m] = y.z; Bs[k4 + 3][m] = y.w;
        }
        __syncthreads();
#pragma unroll
        for (int k = 0; k < 16; ++k) {
            float4 a0 = *(const float4*)&As[k][ty * 4];
            float4 a1 = *(const float4*)&As[k][64 + ty * 4];
            float4 b0 = *(const float4*)&Bs[k][tx * 4];
            float4 b1 = *(const float4*)&Bs[k][64 + tx * 4];
            float av[8]  = {a0.x, a0.y, a0.z, a0.w, a1.x, a1.y, a1.z, a1.w};
            float bv8[8] = {b0.x, b0.y, b0.z, b0.w, b1.x, b1.y, b1.z, b1.w};
#pragma unroll
            for (int i = 0; i < 8; ++i)
#pragma unroll
                for (int j = 0; j < 8; ++j) acc[i][j] += av[i] * bv8[j];
        }
        __syncthreads();
    }
    float4 ml = *(const float4*)&mask[b * S_ + n0 + tx * 4];
    float4 mh = *(const float4*)&mask[b * S_ + n0 + 64 + tx * 4];
    float* C = attn + (size_t)z * S_ * S_;
#pragma unroll
    for (int ii = 0; ii < 8; ++ii) {
        int m = m0 + ((ii >> 2) << 6) + ty * 4 + (ii & 3);
        float4 lo = make_float4(acc[ii][0] * SCALE_ - 1e9f * ml.x,
                                acc[ii][1] * SCALE_ - 1e9f * ml.y,
                                acc[ii][2] * SCALE_ - 1e9f * ml.z,
                                acc[ii][3] * SCALE_ - 1e9f * ml.w);
        *(float4*)&C[(size_t)m * S_ + n0 + tx * 4] = lo;
        float4 hi = make_float4(acc[ii][4] * SCALE_ - 1e9f * mh.x,
                                acc[ii][5] * SCALE_ - 1e9f * mh.y,
                                acc[ii][6] * SCALE_ - 1e9f * mh.z,
                                acc[ii][7] * SCALE_ - 1e9f * mh.w);
        *(float4*)&C[(size_t)m * S_ + n0 + 64 + tx * 4] = hi;
    }
}

// one block per row of 2048 (HBM-bound, ~its roofline already)
__global__ __launch_bounds__(256) void softmax_kernel(float* __restrict__ attn)
{
    const size_t row = blockIdx.x;
    float4* p4 = (float4*)(attn + row * S_);
    const int tid = threadIdx.x;
    const int wave = tid >> 6, lane = tid & 63;
    __shared__ float redm[4];
    __shared__ float reds[4];

    float4 x0 = p4[tid];
    float4 x1 = p4[tid + 256];
    float m = fmaxf(fmaxf(fmaxf(x0.x, x0.y), fmaxf(x0.z, x0.w)),
                    fmaxf(fmaxf(x1.x, x1.y), fmaxf(x1.z, x1.w)));
#pragma unroll
    for (int off = 32; off; off >>= 1) m = fmaxf(m, __shfl_down(m, off, 64));
    if (lane == 0) redm[wave] = m;
    __syncthreads();
    m = fmaxf(fmaxf(redm[0], redm[1]), fmaxf(redm[2], redm[3]));

    x0.x = expf(x0.x - m); x0.y = expf(x0.y - m);
    x0.z = expf(x0.z - m); x0.w = expf(x0.w - m);
    x1.x = expf(x1.x - m); x1.y = expf(x1.y - m);
    x1.z = expf(x1.z - m); x1.w = expf(x1.w - m);
    float s = x0.x + x0.y + x0.z + x0.w + x1.x + x1.y + x1.z + x1.w;
#pragma unroll
    for (int off = 32; off; off >>= 1) s += __shfl_down(s, off, 64);
    if (lane == 0) reds[wave] = s;
    __syncthreads();
    s = reds[0] + reds[1] + reds[2] + reds[3];
    float inv = 1.0f / s;
    x0.x *= inv; x0.y *= inv; x0.z *= inv; x0.w *= inv;
    x1.x *= inv; x1.y *= inv; x1.z *= inv; x1.w *= inv;
    p4[tid] = x0;
    p4[tid + 256] = x1;
}

// ctx[z] = attn[z] (2048x2048) @ vh[z] (2048x64) -> merged-head [B,S,D].
// Tile 128(M)x64(N), 8x4 micro. 512 blocks = 2 blocks/CU.
__global__ __launch_bounds__(256) void ctx_kernel(
    const float* __restrict__ attn, const float* __restrict__ vh,
    float* __restrict__ ctx)
{
    const int z = blockIdx.y;
    const int b = z >> 4, h = z & 15;
    const float* A = attn + (size_t)z * S_ * S_;
    const float* V = vh + (size_t)z * S_ * DEPTH_;
    __shared__ float As[16][132];
    __shared__ float Bs[16][68];
    const int tid = threadIdx.x;
    const int tx = tid & 15, ty = tid >> 4;
    const int m0 = blockIdx.x * 128;
    float acc[8][4] = {};

    for (int kk = 0; kk < S_; kk += 16) {
        int f = tid;
#pragma unroll
        for (int r = 0; r < 2; ++r, f += 256) {
            int m = f >> 2, k4 = (f & 3) << 2;
            float4 x = *(const float4*)&A[(size_t)(m0 + m) * S_ + kk + k4];
            As[k4 + 0][m] = x.x; As[k4 + 1][m] = x.y;
            As[k4 + 2][m] = x.z; As[k4 + 3][m] = x.w;
        }
        {
            int k = tid >> 4, n4 = (tid & 15) << 2;
            *(float4*)&Bs[k][n4] = *(const float4*)&V[(size_t)(kk + k) * DEPTH_ + n4];
        }
        __syncthreads();
#pragma unroll
        for (int k = 0; k < 16; ++k) {
            float4 a0 = *(const float4*)&As[k][ty * 4];
            float4 a1 = *(const float4*)&As[k][64 + ty * 4];
            float4 b0 = *(const float4*)&Bs[k][tx * 4];
            float av[8]  = {a0.x, a0.y, a0.z, a0.w, a1.x, a1.y, a1.z, a1.w};
            float bv4[4] = {b0.x, b0.y, b0.z, b0.w};
#pragma unroll
            for (int i = 0; i < 8; ++i)
#pragma unroll
                for (int j = 0; j < 4; ++j) acc[i][j] += av[i] * bv4[j];
        }
        __syncthreads();
    }
#pragma unroll
    for (int ii = 0; ii < 8; ++ii) {
        int s = m0 + ((ii >> 2) << 6) + ty * 4 + (ii & 3);
        float4 r4 = make_float4(acc[ii][0], acc[ii][1], acc[ii][2], acc[ii][3]);
        *(float4*)&ctx[((size_t)(b * S_ + s)) * D_ + h * DEPTH_ + tx * 4] = r4;
    }
}

// out = ctx[4096,1024] @ Wo + bo, plain row-major
__global__ __launch_bounds__(256) void out_kernel(
    const float* __restrict__ X, const float* __restrict__ W,
    const float* __restrict__ bias, float* __restrict__ out)
{
    __shared__ float As[16][132];
    __shared__ float Bs[16][132];
    const int tid = threadIdx.x;
    const int tx = tid & 15, ty = tid >> 4;
    const int m0 = blockIdx.y * 128;
    const int n0 = blockIdx.x * 128;
    float acc[8][8] = {};

    for (int kk = 0; kk < D_; kk += 16) {
        int f = tid;
#pragma unroll
        for (int r = 0; r < 2; ++r, f += 256) {
            int m = f >> 2, k4 = (f & 3) << 2;
            float4 x = *(const float4*)&X[(size_t)(m0 + m) * D_ + kk + k4];
            As[k4 + 0][m] = x.x; As[k4 + 1][m] = x.y;
            As[k4 + 2][m] = x.z; As[k4 + 3][m] = x.w;
        }
        f = tid;
#pragma unroll
        for (int r = 0; r < 2; ++r, f += 256) {
            int k = f >> 5, n4 = (f & 31) << 2;
            *(float4*)&Bs[k][n4] = *(const float4*)&W[(size_t)(kk + k) * D_ + n0 + n4];
        }
        __syncthreads();
#pragma unroll
        for (int k = 0; k < 16; ++k) {
            float4 a0 = *(const float4*)&As[k][ty * 4];
            float4 a1 = *(const float4*)&As[k][64 + ty * 4];
            float4 b0 = *(const float4*)&Bs[k][tx * 4];
            float4 b1 = *(const float4*)&Bs[k][64 + tx * 4];
            float av[8]  = {a0.x, a0.y, a0.z, a0.w, a1.x, a1.y, a1.z, a1.w};
            float bv8[8] = {b0.x, b0.y, b0.z, b0.w, b1.x, b1.y, b1.z, b1.w};
#pragma unroll
            for (int i = 0; i < 8; ++i)
#pragma unroll
                for (int j = 0; j < 8; ++j) acc[i][j] += av[i] * bv8[j];
        }
        __syncthreads();
    }
    float4 bl = *(const float4*)&bias[n0 + tx * 4];
    float4 bh = *(const float4*)&bias[n0 + 64 + tx * 4];
#pragma unroll
    for (int ii = 0; ii < 8; ++ii) {
        int m = m0 + ((ii >> 2) << 6) + ty * 4 + (ii & 3);
        float4 lo = make_float4(acc[ii][0] + bl.x, acc[ii][1] + bl.y,
                                acc[ii][2] + bl.z, acc[ii][3] + bl.w);
        *(float4*)&out[(size_t)m * D_ + n0 + tx * 4] = lo;
        float4 hi = make_float4(acc[ii][4] + bh.x, acc[ii][5] + bh.y,
                                acc[ii][6] + bh.z, acc[ii][7] + bh.w);
        *(float4*)&out[(size_t)m * D_ + n0 + 64 + tx * 4] = hi;
    }
}

extern "C" void kernel_launch(void* const* d_in, const int* in_sizes, int n_in,
                              void* d_out, int out_size, void* d_ws, size_t ws_size,
                              hipStream_t stream)
{
    const float* q    = (const float*)d_in[0];
    const float* k    = (const float*)d_in[1];
    const float* v    = (const float*)d_in[2];
    const float* mask = (const float*)d_in[3];
    const float* Wq   = (const float*)d_in[4];
    const float* bq   = (const float*)d_in[5];
    const float* Wk   = (const float*)d_in[6];
    const float* bk   = (const float*)d_in[7];
    const float* Wv   = (const float*)d_in[8];
    const float* bv   = (const float*)d_in[9];
    const float* Wo   = (const float*)d_in[10];
    const float* bo   = (const float*)d_in[11];

    float* out  = (float*)d_out;
    float* attn = out + (size_t)B_ * S_ * D_;   // second output

    float* ws  = (float*)d_ws;
    float* qh  = ws;                                  // [B,H,S,64]
    float* kh  = qh + (size_t)B_ * S_ * D_;
    float* vh  = kh + (size_t)B_ * S_ * D_;
    float* ctx = vh + (size_t)B_ * S_ * D_;           // [B,S,D]

    dim3 blk(256);

    // fused Q/K/V projections: grid (N/128, M/128, 3) = (8, 32, 3)
    qkv_proj_kernel<<<dim3(8, 32, 3), blk, 0, stream>>>(
        q, k, v, Wq, bq, Wk, bk, Wv, bv, qh, kh, vh);

    // logits: grid (S/128, S/128, B*H) = (16, 16, 32)
    logits_kernel<<<dim3(16, 16, 32), blk, 0, stream>>>(qh, kh, mask, attn);

    softmax_kernel<<<dim3(B_ * H_ * S_), blk, 0, stream>>>(attn);

    // ctx: grid (S/128, B*H) = (16, 32)
    ctx_kernel<<<dim3(16, 32), blk, 0, stream>>>(attn, vh, ctx);

    // out: grid (8, 32)
    out_kernel<<<dim3(8, 32), blk, 0, stream>>>(ctx, Wo, bo, out);
}